// Round 3
// baseline (1089.384 us; speedup 1.0000x reference)
//
#include <hip/hip_runtime.h>

// VecLeadingZeroDetector108: X [n_rows, 108] float32 bits (exact 0.0/1.0),
// out [n_rows, 7] float32 = binary (MSB-first) index of first set bit, or
// 108 = 1101100b if the row is all zero.
//
// R2: coalesced + branchless + atomic-free. Block of 256 threads owns 256
// consecutive rows (contiguous 256*27 float4 region). Phase 1: sweep with
// coalesced float4 loads; 4 ballots per load give the nonzero bits of 64
// consecutive f4s; lanes 0..7 Morton-interleave the four 8-bit ballot slices
// into one u32 each and ds_write — all 864 words of the per-tile bit image
// are written exactly once (no zero-init, no atomics, no load-dependent
// branches, so per-wave loads stay pipelined). Phase 2: thread t extracts its
// row's 108-bit window from 5 LDS words via 64-bit funnel shifts, __ffs,
// encode 7 bits, coalesced float4 writeback.

#define NBITS 108
#define NOUT 7
#define RPB 256                        // rows per block == blockDim.x
#define F4R 27                         // float4 per row
#define WORDS (RPB * NBITS / 32)       // 864 u32 of packed bits per tile

__device__ __forceinline__ unsigned spread4(unsigned x) {
    // 8 bits -> 32 bits, gap 4: bit i -> bit 4i
    x = (x | (x << 12)) & 0x000F000Fu;
    x = (x | (x << 6))  & 0x03030303u;
    x = (x | (x << 3))  & 0x11111111u;
    return x;
}

__global__ __launch_bounds__(256) void lzd108_kernel(const uint4* __restrict__ X4,
                                                     float* __restrict__ out,
                                                     int n_rows) {
    __shared__ unsigned Wb[WORDS + 4];               // +4 pad: phase-2 reads 5 words
    __shared__ __align__(16) float obuf[RPB * NOUT]; // output staging

    const int tid = threadIdx.x;
    const int lane = tid & 63;
    const int wv = tid >> 6;
    const long long row0 = (long long)blockIdx.x * RPB;
    int rows_here = n_rows - (int)row0;
    if (rows_here > RPB) rows_here = RPB;

    if (rows_here < RPB) {
        // Tail block (at most one in the grid): simple scalar path.
        if (tid < rows_here) {
            const unsigned* r = reinterpret_cast<const unsigned*>(X4) + (row0 + tid) * NBITS;
            int idx = NBITS;
            for (int j = 0; j < NBITS; ++j) {
                if (r[j] != 0u) { idx = j; break; }
            }
            float* o = out + (row0 + tid) * NOUT;
            o[0] = (float)((idx >> 6) & 1);
            o[1] = (float)((idx >> 5) & 1);
            o[2] = (float)((idx >> 4) & 1);
            o[3] = (float)((idx >> 3) & 1);
            o[4] = (float)((idx >> 2) & 1);
            o[5] = (float)((idx >> 1) & 1);
            o[6] = (float)(idx & 1);
        }
        return;
    }

    // ---- Phase 1: coalesced sweep, ballot-pack into LDS bit image ----
    const uint4* base = X4 + row0 * F4R;
    #pragma unroll 3
    for (int i = 0; i < F4R; ++i) {
        uint4 v = base[i * RPB + tid];
        unsigned long long bx = __ballot(v.x != 0u);
        unsigned long long by = __ballot(v.y != 0u);
        unsigned long long bz = __ballot(v.z != 0u);
        unsigned long long bw = __ballot(v.w != 0u);
        if (lane < 8) {
            const unsigned s8 = (unsigned)lane << 3;
            unsigned word = spread4((unsigned)(bx >> s8) & 0xFFu)
                          | (spread4((unsigned)(by >> s8) & 0xFFu) << 1)
                          | (spread4((unsigned)(bz >> s8) & 0xFFu) << 2)
                          | (spread4((unsigned)(bw >> s8) & 0xFFu) << 3);
            // word d covers global-f4 q = i*256 + 64*wv + 8*lane .. +8
            Wb[32 * i + 8 * wv + lane] = word;
        }
    }
    __syncthreads();

    // ---- Phase 2: per-row ffs over the 108-bit window ----
    {
        const int g = NBITS * tid;        // start bit of row `tid` in the image
        const int w0 = g >> 5;
        const unsigned sh = (unsigned)(g & 31);
        const unsigned a = Wb[w0];
        const unsigned b = Wb[w0 + 1];
        const unsigned c = Wb[w0 + 2];
        const unsigned d = Wb[w0 + 3];
        const unsigned e = Wb[w0 + 4];
        // 64-bit funnels (sh < 32, no UB; sh==0 degenerates correctly)
        unsigned r0 = (unsigned)((((unsigned long long)b << 32) | a) >> sh);
        unsigned r1 = (unsigned)((((unsigned long long)c << 32) | b) >> sh);
        unsigned r2 = (unsigned)((((unsigned long long)d << 32) | c) >> sh);
        unsigned r3 = (unsigned)((((unsigned long long)e << 32) | d) >> sh);
        r3 &= 0xFFFu;                     // bits 96..107 only
        int idx;
        if (r0)      idx =      __ffs(r0) - 1;
        else if (r1) idx = 32 + __ffs(r1) - 1;
        else if (r2) idx = 64 + __ffs(r2) - 1;
        else if (r3) idx = 96 + __ffs(r3) - 1;
        else         idx = NBITS;
        float* o = &obuf[tid * NOUT];
        o[0] = (float)((idx >> 6) & 1);
        o[1] = (float)((idx >> 5) & 1);
        o[2] = (float)((idx >> 4) & 1);
        o[3] = (float)((idx >> 3) & 1);
        o[4] = (float)((idx >> 2) & 1);
        o[5] = (float)((idx >> 1) & 1);
        o[6] = (float)(idx & 1);
    }
    __syncthreads();

    // ---- Coalesced writeback: 256*7 floats = 448 float4 ----
    float4* g4 = reinterpret_cast<float4*>(out + row0 * NOUT);
    const float4* s4 = reinterpret_cast<const float4*>(obuf);
    #pragma unroll
    for (int it = 0; it < 2; ++it) {
        const int q = it * RPB + tid;
        if (q < (RPB * NOUT) / 4) g4[q] = s4[q];
    }
}

extern "C" void kernel_launch(void* const* d_in, const int* in_sizes, int n_in,
                              void* d_out, int out_size, void* d_ws, size_t ws_size,
                              hipStream_t stream) {
    const uint4* X4 = (const uint4*)d_in[0];
    float* out = (float*)d_out;
    const int n_rows = in_sizes[0] / NBITS;
    const int grid = (n_rows + RPB - 1) / RPB;
    lzd108_kernel<<<grid, RPB, 0, stream>>>(X4, out, n_rows);
}